// Round 14
// baseline (128.398 us; speedup 1.0000x reference)
//
#include <hip/hip_runtime.h>
#include <hip/hip_bf16.h>

#define BS 4096
#define D 256
#define NROW 8192      // 2*BS
#define INV_T 2.0f

typedef short short8 __attribute__((ext_vector_type(8)));
typedef float f32x4 __attribute__((ext_vector_type(4)));

__device__ __forceinline__ unsigned short f2b(float x) {
    __hip_bfloat16 h = __float2bfloat16(x);
    return *reinterpret_cast<unsigned short*>(&h);
}
__device__ __forceinline__ float b2f(unsigned short b) {
    unsigned int u = ((unsigned int)b) << 16;
    return __uint_as_float(u);
}

// K1: normalize rows of zi/zj -> bf16 W [8192][256]; zero rowsum + accum(3).
__global__ __launch_bounds__(256) void k_norm(const float* __restrict__ zi,
                                              const float* __restrict__ zj,
                                              unsigned short* __restrict__ W,
                                              float* __restrict__ rowsum,
                                              float* __restrict__ accum) {
    const int gt   = blockIdx.x * 256 + threadIdx.x;
    const int wave = gt >> 6;
    const int lane = threadIdx.x & 63;

    const float* src = (wave < BS) ? (zi + (size_t)wave * D)
                                   : (zj + (size_t)(wave - BS) * D);
    float4 v = reinterpret_cast<const float4*>(src)[lane];
    float ss = v.x * v.x + v.y * v.y + v.z * v.z + v.w * v.w;
#pragma unroll
    for (int m = 1; m < 64; m <<= 1) ss += __shfl_xor(ss, m, 64);
    float inv = rsqrtf(ss);

    ushort4 o;
    o.x = f2b(v.x * inv);
    o.y = f2b(v.y * inv);
    o.z = f2b(v.z * inv);
    o.w = f2b(v.w * inv);
    reinterpret_cast<ushort4*>(W + (size_t)wave * D)[lane] = o;

    if (gt < NROW) rowsum[gt] = 0.0f;
    if (gt < 3)    accum[gt]  = 0.0f;   // [0]=lse, [1]=pos, [2]=done ctr
}

// K2: block = 128 rows x 64 cols of the upper triangle (bj >= 2*bi).
// A (128x256) in REGISTERS; B (64x256) staged to LDS ONCE via global_load_lds,
// subtiled [8 kstep][64 rows][32 elems] (64B rows -> bank-uniform ds_read_b128,
// no swizzle needed). ONE barrier per block, with an EXPLICIT vmcnt(0) drain +
// sched_barrier fences (r13's implicit-drain version intermittently raced:
// NaN tripwire). Wedge blocks (bj-2bi<2) mask gc<=gr; every block adds its
// exp-sums to BOTH row and col rowsum entries (each pair counted exactly once).
__global__ __launch_bounds__(256, 3) void k_gemm(const unsigned short* __restrict__ W,
                                                 float* __restrict__ rowsum) {
    __shared__ unsigned short lB[8][64][32];   // 32 KB

    const int tid  = threadIdx.x;
    const int lane = tid & 63;
    const int w    = tid >> 6;      // wave 0..3

    // decode t -> (bi, bj): f(bi) = bi*(129-bi) blocks before row-block bi
    const int t = blockIdx.x;
    int bi = (int)((129.0f - sqrtf(16641.0f - 4.0f * (float)t)) * 0.5f);
    while (bi > 0 && bi * (129 - bi) > t) --bi;
    while ((bi + 1) * (129 - (bi + 1)) <= t) ++bi;
    bi = min(max(bi, 0), 63);                       // safety clamp (in-bounds)
    int bj = 2 * bi + (t - bi * (129 - bi));
    bj = min(max(bj, 0), 127);
    const int R0 = bi * 128;
    const int C0 = bj * 64;
    const bool wedge = (bj - 2 * bi) < 2;   // block touches the diagonal

    // ---- B into LDS once: wave w stages ksteps {2w, 2w+1} (DMA first) ----
#pragma unroll
    for (int kq = 0; kq < 2; ++kq) {
        const int ks = w * 2 + kq;
#pragma unroll
        for (int c = 0; c < 4; ++c) {
            const int row = c * 16 + (lane >> 2);
            const unsigned short* g =
                W + (size_t)(C0 + row) * D + ks * 32 + (lane & 3) * 8;
            __builtin_amdgcn_global_load_lds(
                (const __attribute__((address_space(1))) void*)g,
                (__attribute__((address_space(3))) void*)(&lB[ks][c * 16][0]),
                16, 0, 0);
        }
    }

    // ---- A into registers ----
    short8 a[2][8];
    {
        const int r  = R0 + w * 32 + (lane & 15);
        const int kc = (lane >> 4) * 8;
#pragma unroll
        for (int mi = 0; mi < 2; ++mi)
#pragma unroll
            for (int ks = 0; ks < 8; ++ks)
                a[mi][ks] = *reinterpret_cast<const short8*>(
                    W + (size_t)(r + mi * 16) * D + ks * 32 + kc);
    }

    // ---- explicit drain: DMA landed in LDS + A in regs, for THIS wave ----
    asm volatile("s_waitcnt vmcnt(0)" ::: "memory");
    __builtin_amdgcn_sched_barrier(0);
    __syncthreads();                     // join: now ALL waves' DMA landed
    __builtin_amdgcn_sched_barrier(0);   // pin ds_reads below the barrier

    // ---- K loop: 8 ksteps, barrier-free ----
    f32x4 acc[2][4] = {};
#pragma unroll
    for (int ks = 0; ks < 8; ++ks) {
        short8 b[4];
#pragma unroll
        for (int ni = 0; ni < 4; ++ni) {
            const int row = ni * 16 + (lane & 15);
            b[ni] = *reinterpret_cast<const short8*>(&lB[ks][row][(lane >> 4) * 8]);
        }
#pragma unroll
        for (int mi = 0; mi < 2; ++mi)
#pragma unroll
            for (int ni = 0; ni < 4; ++ni)
                acc[mi][ni] = __builtin_amdgcn_mfma_f32_16x16x32_bf16(
                    a[mi][ks], b[ni], acc[mi][ni], 0, 0, 0);
    }

    // ---- Epilogue. C/D: col = lane&15, row = (lane>>4)*4 + j ----
    const int rbase = R0 + w * 32 + (lane >> 4) * 4;
    float colacc[4] = {0.f, 0.f, 0.f, 0.f};
#pragma unroll
    for (int mi = 0; mi < 2; ++mi) {
#pragma unroll
        for (int j = 0; j < 4; ++j) {
            const int gr = rbase + mi * 16 + j;
            float s = 0.0f;
#pragma unroll
            for (int ni = 0; ni < 4; ++ni) {
                const int gc = C0 + ni * 16 + (lane & 15);
                float e = __expf(acc[mi][ni][j] * INV_T);
                if (wedge && gc <= gr) e = 0.0f;
                s += e;
                colacc[ni] += e;
            }
            s += __shfl_xor(s, 1, 64);
            s += __shfl_xor(s, 2, 64);
            s += __shfl_xor(s, 4, 64);
            s += __shfl_xor(s, 8, 64);
            if ((lane & 15) == 0) atomicAdd(&rowsum[gr], s);
        }
    }
#pragma unroll
    for (int ni = 0; ni < 4; ++ni) {
        float cs = colacc[ni];
        cs += __shfl_xor(cs, 16, 64);
        cs += __shfl_xor(cs, 32, 64);
        if ((lane >> 4) == 0)
            atomicAdd(&rowsum[C0 + ni * 16 + lane], cs);
    }
}

// K3: lse_sum = sum(log(rowsum)); pos_sum = sum_i 2*dot(u_i,v_i);
// last finished block writes the final loss.
__global__ __launch_bounds__(256) void k_finalize(const unsigned short* __restrict__ W,
                                                  const float* __restrict__ rowsum,
                                                  float* __restrict__ accum,
                                                  float* __restrict__ out) {
    const int tid  = blockIdx.x * 256 + threadIdx.x;  // 32 blocks -> 8192 threads
    const int lane = threadIdx.x & 63;

    float l = logf(rowsum[tid]);
#pragma unroll
    for (int m = 1; m < 64; m <<= 1) l += __shfl_xor(l, m, 64);
    if (lane == 0) atomicAdd(&accum[0], l);

    const int wgid = tid >> 6;
    float pacc = 0.0f;
    for (int t = 0; t < 32; ++t) {
        const int i = wgid * 32 + t;
        ushort4 ub = reinterpret_cast<const ushort4*>(W + (size_t)i * D)[lane];
        ushort4 vb = reinterpret_cast<const ushort4*>(W + (size_t)(BS + i) * D)[lane];
        pacc += b2f(ub.x) * b2f(vb.x) + b2f(ub.y) * b2f(vb.y)
              + b2f(ub.z) * b2f(vb.z) + b2f(ub.w) * b2f(vb.w);
    }
#pragma unroll
    for (int m = 1; m < 64; m <<= 1) pacc += __shfl_xor(pacc, m, 64);
    if (lane == 0) atomicAdd(&accum[1], INV_T * pacc);

    __syncthreads();                 // block's atomics issued & drained
    if (threadIdx.x == 0) {
        __threadfence();
        int* done = (int*)(accum + 2);
        if (atomicAdd(done, 1) == 31) {          // last of 32 blocks
            float a0 = atomicAdd(&accum[0], 0.0f);   // coherent read
            float a1 = atomicAdd(&accum[1], 0.0f);
            out[0] = a0 * (1.0f / NROW) - a1 * (1.0f / BS);
        }
    }
}

extern "C" void kernel_launch(void* const* d_in, const int* in_sizes, int n_in,
                              void* d_out, int out_size, void* d_ws, size_t ws_size,
                              hipStream_t stream) {
    const float* zi = (const float*)d_in[0];
    const float* zj = (const float*)d_in[1];
    float* out = (float*)d_out;

    unsigned short* W = (unsigned short*)d_ws;                        // 4 MB
    float* rowsum = (float*)((char*)d_ws + (size_t)NROW * D * 2);     // 32 KB
    float* accum  = rowsum + NROW;                                    // 12 B

    k_norm<<<NROW / 4, 256, 0, stream>>>(zi, zj, W, rowsum, accum);
    k_gemm<<<4160, 256, 0, stream>>>(W, rowsum);
    k_finalize<<<32, 256, 0, stream>>>(W, rowsum, accum, out);
}